// Round 3
// baseline (339.637 us; speedup 1.0000x reference)
//
#include <hip/hip_runtime.h>
#include <stdint.h>

typedef __bf16 bf16_t;
typedef __bf16 bf16x8 __attribute__((ext_vector_type(8)));
typedef __bf16 bf16x4 __attribute__((ext_vector_type(4)));
typedef float  f32x4  __attribute__((ext_vector_type(4)));

#define DEV __device__ __forceinline__

constexpr int S = 2048, D = 1024, BATCH = 4, MF = BATCH * S;

// async global->LDS, 16B per lane. LDS dest is wave-uniform base + lane*16.
DEV void gload16(const void* g, void* l) {
  __builtin_amdgcn_global_load_lds(
      (const __attribute__((address_space(1))) void*)g,
      (__attribute__((address_space(3))) void*)(uint32_t)(uintptr_t)l,
      16, 0, 0);
}

// ---------------------------------------------------------------------------
// bf16 NT GEMM body: C[m][n] = sum_k A[m][k]*B[n][k], fp32 acc.
// Tile 128x128, BK=64, 256 thr (4 waves, 2x2 of 64x64). 16-B chunks
// XOR-swizzled by (row&7) on the GLOBAL source side -> 0 bank conflicts.
// EP: 1 = QKV split: q/k -> fp8 [MF][D], vw transposed bf16 -> vwT[b][D][S]
//     3 = FINAL: out = acc * invl[row] + bo[n], fp32 (PV with folded Wo)
//     4 = plain bf16 out, ldc = D (WvoT precompute)
// ---------------------------------------------------------------------------
template<int EP>
DEV void gemm_body(int tm, int tn, int bz,
                   const bf16_t* __restrict__ A, const bf16_t* __restrict__ B,
                   void* __restrict__ C0, void* __restrict__ C1,
                   void* __restrict__ C2, const float* __restrict__ aux,
                   int K, int kmax, bf16_t* ldsA, bf16_t* ldsB)
{
  const int m0 = tm * 128, n0 = tn * 128;
  const int tid  = threadIdx.x;
  const int lane = tid & 63;
  const int wave = tid >> 6;
  const int wm = wave & 1, wn = wave >> 1;
  const int l8r = lane >> 3;                  // row within 8-row staging block
  const int swz = ((lane & 7) ^ (lane >> 3)) * 8;  // swizzled k-chunk (elems)
  const int cl  = lane & 15;                  // fragment m/n index
  const int qd  = lane >> 4;                  // quad -> k-slice
  const int ch0 = ((qd ^ (cl & 7)) * 8);      // swizzled read chunk, kk=0

  f32x4 acc[4][4] = {};

  for (int k0 = 0; k0 < kmax; k0 += 64) {
    #pragma unroll
    for (int t = 0; t < 4; ++t) {
      const int rb = wave * 4 + t;
      gload16(A + (long)(m0 + rb * 8 + l8r) * K + (k0 + swz), &ldsA[rb * 512]);
      gload16(B + (long)(n0 + rb * 8 + l8r) * K + (k0 + swz), &ldsB[rb * 512]);
    }
    __syncthreads();
    #pragma unroll
    for (int kk = 0; kk < 64; kk += 32) {
      bf16x8 af[4], bg[4];
      #pragma unroll
      for (int i = 0; i < 4; ++i)
        af[i] = *(const bf16x8*)&ldsA[(wm * 64 + i * 16 + cl) * 64 + (ch0 ^ kk)];
      #pragma unroll
      for (int j = 0; j < 4; ++j)
        bg[j] = *(const bf16x8*)&ldsB[(wn * 64 + j * 16 + cl) * 64 + (ch0 ^ kk)];
      #pragma unroll
      for (int i = 0; i < 4; ++i)
        #pragma unroll
        for (int j = 0; j < 4; ++j)
          acc[i][j] = __builtin_amdgcn_mfma_f32_16x16x32_bf16(af[i], bg[j], acc[i][j], 0, 0, 0);
    }
    __syncthreads();
  }

  // Epilogues. C/D layout: col = lane&15, row = (lane>>4)*4 + reg.
  #pragma unroll
  for (int i = 0; i < 4; ++i) {
    const int gm0 = m0 + wm * 64 + i * 16 + qd * 4;

    if (EP == 1) {                            // QK (fp8) + VW (bf16) split
      uint8_t* q8 = (uint8_t*)C0;
      uint8_t* k8 = (uint8_t*)C1;
      bf16_t* vwT = (bf16_t*)C2;
      #pragma unroll
      for (int j = 0; j < 4; ++j) {
        const int gn  = n0 + wn * 64 + j * 16 + cl;
        const int sec = gn >> 10, ln = gn & 1023;
        const float bn = aux[gn];
        if (sec == 2) {                       // vw: store transposed, 4x bf16
          const int z = gm0 >> 11, s0 = gm0 & 2047;
          bf16x4 v4;
          #pragma unroll
          for (int r = 0; r < 4; ++r) v4[r] = (bf16_t)(acc[i][j][r] + bn);
          *(bf16x4*)&vwT[((long)z * D + ln) * S + s0] = v4;
        } else {
          uint8_t* dst = (sec == 0) ? q8 : k8;
          #pragma unroll
          for (int r = 0; r < 4; ++r) {
            const float v = acc[i][j][r] + bn;
            const int p = __builtin_amdgcn_cvt_pk_fp8_f32(v, v, 0, false);
            dst[(long)(gm0 + r) * D + ln] = (uint8_t)(p & 0xFF);
          }
        }
      }
    }

    if (EP == 3) {                            // FINAL: fp32 out, invl + bo
      float* out = (float*)C0 + (long)bz * S * D;
      const float* invl = aux + (long)bz * S;
      const float* bo = (const float*)C1;
      float scl[4];
      #pragma unroll
      for (int r = 0; r < 4; ++r) scl[r] = invl[gm0 + r];
      #pragma unroll
      for (int j = 0; j < 4; ++j) {
        const int gn = n0 + wn * 64 + j * 16 + cl;
        const float bn = bo[gn];
        #pragma unroll
        for (int r = 0; r < 4; ++r)
          out[(long)(gm0 + r) * D + gn] = acc[i][j][r] * scl[r] + bn;
      }
    }

    if (EP == 4) {                            // plain bf16 out (Wvo precomp)
      bf16_t* Co = (bf16_t*)C0;
      #pragma unroll
      for (int j = 0; j < 4; ++j) {
        const int gn = n0 + wn * 64 + j * 16 + cl;
        #pragma unroll
        for (int r = 0; r < 4; ++r)
          Co[(long)(gm0 + r) * D + gn] = (bf16_t)acc[i][j][r];
      }
    }
  }
}

// QK+VW projection: 1536 blocks, XCD-bijective swizzle (1536 % 8 == 0).
// HW block h -> XCD h%8 (round-robin). Each XCD owns a contiguous tn-range
// of 3 B-panels (3 x 256KB, L2-resident); A streams once HBM->L3.
// j = (h&7)*192 + h>>3; tn = j/64 (0..23), tm = j%64.
__global__ __launch_bounds__(256, 5) void gemm_qkv(
    const bf16_t* __restrict__ A, const bf16_t* __restrict__ B,
    uint8_t* q8, uint8_t* k8, bf16_t* vwT, const float* __restrict__ bias)
{
  __shared__ __align__(16) bf16_t lA[128 * 64], lB[128 * 64];
  const int h = blockIdx.x;
  const int j = (h & 7) * 192 + (h >> 3);
  const int tn = j >> 6, tm = j & 63;
  gemm_body<1>(tm, tn, 0, A, B, q8, k8, vwT, bias,
               1024, 1024, lA, lB);
}

// ---------------------------------------------------------------------------
// fp8 scores kernel: probs = exp(q8·k8^T / 32) causal, bf16 + partial sums.
// Same 128x128 tile geometry; LDS rows = 64 fp8 = 64 B. 16-B granules
// XOR-swizzled by (row>>1)&3 (global-source side) -> <=2-way conflicts (free).
// mfma_f32_16x16x32_fp8_fp8: A/B operand = 8 bytes (long), k = quad*8+[0..7].
// 544 blocks, blockIdx%8 = XCD, 2 XCDs/batch, 68-tile triangle halves.
// ---------------------------------------------------------------------------
__global__ __launch_bounds__(256, 4) void gemm_sc8(
    const uint8_t* __restrict__ q8g, const uint8_t* __restrict__ k8g,
    bf16_t* __restrict__ probs_g, float* __restrict__ part)
{
  __shared__ __align__(16) uint8_t lA[128 * 64], lB[128 * 64];
  const int l = blockIdx.x, xcd = l & 7, idx = l >> 3;
  const int bz = xcd >> 1;
  const int t  = (xcd & 1) * 68 + idx;             // triangular index 0..135
  int tm = (int)((sqrtf(8.0f * t + 1.0f) - 1.0f) * 0.5f);
  while ((tm + 1) * (tm + 2) / 2 <= t) ++tm;
  while (tm * (tm + 1) / 2 > t) --tm;
  const int tn = t - tm * (tm + 1) / 2;
  const int m0 = tm * 128, n0 = tn * 128;
  const uint8_t* q8 = q8g + (long)bz * S * D;
  const uint8_t* k8 = k8g + (long)bz * S * D;

  const int tid  = threadIdx.x;
  const int lane = tid & 63;
  const int wave = tid >> 6;
  const int wm = wave & 1, wn = wave >> 1;
  const int srow = lane >> 2;                      // staging row in 16-slab
  const int sgr  = (lane & 3) ^ ((lane >> 3) & 3); // swizzled source granule
  const int cl = lane & 15, qd = lane >> 4;
  const int sfr = (cl >> 1) & 3;                   // frag-read swizzle key
  const int half8 = (qd & 1) * 8;

  f32x4 acc[4][4] = {};

  for (int k0 = 0; k0 < 1024; k0 += 64) {
    #pragma unroll
    for (int tt = 0; tt < 2; ++tt) {
      const int rb = wave * 2 + tt;                // 16-row slab (0..7)
      const int gr = rb * 16 + srow;
      gload16(q8 + (long)(m0 + gr) * 1024 + k0 + sgr * 16, &lA[rb * 1024]);
      gload16(k8 + (long)(n0 + gr) * 1024 + k0 + sgr * 16, &lB[rb * 1024]);
    }
    __syncthreads();
    #pragma unroll
    for (int kk = 0; kk < 2; ++kk) {
      long a[4], b[4];
      const int pg = ((kk << 1) + (qd >> 1)) ^ sfr;
      #pragma unroll
      for (int i = 0; i < 4; ++i)
        a[i] = *(const long*)&lA[(wm * 64 + i * 16 + cl) * 64 + pg * 16 + half8];
      #pragma unroll
      for (int j = 0; j < 4; ++j)
        b[j] = *(const long*)&lB[(wn * 64 + j * 16 + cl) * 64 + pg * 16 + half8];
      #pragma unroll
      for (int i = 0; i < 4; ++i)
        #pragma unroll
        for (int j = 0; j < 4; ++j)
          acc[i][j] = __builtin_amdgcn_mfma_f32_16x16x32_fp8_fp8(a[i], b[j], acc[i][j], 0, 0, 0);
    }
    __syncthreads();
  }

  // epilogue: exp(acc/32) causal -> bf16 probs + partial row sums
  bf16_t* probs = probs_g + (long)bz * S * S;
  #pragma unroll
  for (int i = 0; i < 4; ++i) {
    const int gm0 = m0 + wm * 64 + i * 16 + qd * 4;
    float ls[4] = {0.f, 0.f, 0.f, 0.f};
    #pragma unroll
    for (int j = 0; j < 4; ++j) {
      const int gn = n0 + wn * 64 + j * 16 + cl;
      #pragma unroll
      for (int r = 0; r < 4; ++r) {
        const int gm = gm0 + r;
        const float e = (gn <= gm) ? __expf(acc[i][j][r] * 0.03125f) : 0.0f;
        probs[(long)gm * S + gn] = (bf16_t)e;
        ls[r] += e;
      }
    }
    #pragma unroll
    for (int r = 0; r < 4; ++r) {
      float v = ls[r];
      v += __shfl_xor(v, 1); v += __shfl_xor(v, 2);
      v += __shfl_xor(v, 4); v += __shfl_xor(v, 8);
      if (cl == 0)
        part[((long)bz * S + (gm0 + r)) * 32 + tn * 2 + wn] = v;
    }
  }
}

// Final PV(+folded Wo): 512 blocks, 2 XCDs/batch. Per-CU exact K balance:
// within an XCD (64 blocks on 32 CUs, idx c pairs with c+32), idx<32 take
// long-K m's {15,13,11,9}-half, idx>=32 take {0,2,4,6}+half with matching g
// -> every CU gets exactly 17 k-tiles.
__global__ __launch_bounds__(256, 4) void gemm_pv_out(
    const bf16_t* __restrict__ probs, const bf16_t* __restrict__ vwT,
    float* out, const float* __restrict__ invl, const float* __restrict__ bo)
{
  __shared__ __align__(16) bf16_t lA[128 * 64], lB[128 * 64];
  const int l = blockIdx.x, xcd = l & 7, idx = l >> 3;
  const int bz = xcd >> 1, half = xcd & 1;
  const int g = (idx >> 3) & 3, tn = idx & 7;
  const int tm = (idx < 32) ? (15 - half - 2 * g) : (2 * g + half);
  const int kmax = (tm + 1) * 128;
  gemm_body<3>(tm, tn, bz, probs + (long)bz * S * S, vwT + (long)bz * D * S,
               out, (void*)bo, nullptr, invl, 2048, kmax, lA, lB);
}

// WvoT[c][i] = sum_n Wv[i][n] * Wo[n][c]  (so vw = x @ (Wv@Wo)).
__global__ __launch_bounds__(256, 4) void gemm_wvo(
    const bf16_t* __restrict__ WoT, const bf16_t* __restrict__ WvN,
    bf16_t* WvoT)
{
  __shared__ __align__(16) bf16_t lA[128 * 64], lB[128 * 64];
  gemm_body<4>(blockIdx.x, blockIdx.y, 0, WoT, WvN, WvoT, nullptr, nullptr,
               nullptr, 1024, 1024, lA, lB);
}

// inv_l[row] = 1 / sum(valid partials). Row tile tm has (tm+1)*2 valid entries.
__global__ __launch_bounds__(256) void reduce_invl(
    const float* __restrict__ part, float* __restrict__ invl)
{
  const int r = blockIdx.x * 256 + threadIdx.x;   // 0..MF-1
  const int row = r & (S - 1);
  const int cnt = ((row >> 7) + 1) * 2;
  const float* p = part + (long)r * 32;
  float s = 0.f;
  for (int j = 0; j < cnt; ++j) s += p[j];
  invl[r] = 1.0f / s;
}

// fp32 -> bf16 elementwise (x), 4 elems/thread
__global__ __launch_bounds__(256) void cvt_x(
    const float4* __restrict__ in, bf16x4* __restrict__ out, int n4)
{
  const int i = blockIdx.x * 256 + threadIdx.x;
  if (i >= n4) return;
  float4 f = in[i];
  bf16x4 o;
  o.x = (__bf16)f.x; o.y = (__bf16)f.y; o.z = (__bf16)f.z; o.w = (__bf16)f.w;
  out[i] = o;
}

// Weights -> bf16. z=0: Wq^T -> slot0; z=1: Wk^T -> slot1; z=3: Wo^T -> slot4
// (transposed via LDS). z=2: Wv plain cast (natural [i][n]) -> slot3.
// Slot 2 (WvoT) is filled by gemm_wvo.
__global__ __launch_bounds__(256) void cvt_w_t4(
    const float* __restrict__ W0, const float* __restrict__ W1,
    const float* __restrict__ W2, const float* __restrict__ W3,
    bf16_t* __restrict__ dst)
{
  const int zmap[4] = {0, 1, 3, 4};
  const float* W = (blockIdx.z == 0) ? W0 : (blockIdx.z == 1) ? W1
                 : (blockIdx.z == 2) ? W2 : W3;
  bf16_t* WT = dst + (size_t)zmap[blockIdx.z] * D * D;
  const int bx = blockIdx.x, by = blockIdx.y;
  const int tx = threadIdx.x & 31, ty = threadIdx.x >> 5;  // 32 x 8

  if (blockIdx.z == 2) {                      // Wv: plain cast, no transpose
    #pragma unroll
    for (int dy = 0; dy < 32; dy += 8) {
      const long idx = (long)(by * 32 + ty + dy) * 1024 + bx * 32 + tx;
      WT[idx] = (bf16_t)W[idx];
    }
    return;
  }

  __shared__ float t[32][33];
  #pragma unroll
  for (int dy = 0; dy < 32; dy += 8)
    t[ty + dy][tx] = W[(long)(by * 32 + ty + dy) * 1024 + bx * 32 + tx];
  __syncthreads();
  #pragma unroll
  for (int dy = 0; dy < 32; dy += 8)
    WT[(long)(bx * 32 + ty + dy) * 1024 + by * 32 + tx] = (bf16_t)t[tx][ty + dy];
}

// bias build: blocks 0..255 -> bvo[c] = sum_e bv[e]*WoT[c][e], one wave per
// column (coalesced row read + butterfly). Blocks 256..259 copy bq/bk.
__global__ __launch_bounds__(256) void bias_build(
    const float* __restrict__ bq, const float* __restrict__ bk,
    const float* __restrict__ bv, const bf16_t* __restrict__ WoT,
    float* __restrict__ o)
{
  const int b = blockIdx.x;
  if (b >= 256) {
    const int i = (b - 256) * 256 + threadIdx.x;   // 0..1023
    o[i] = bq[i];
    o[1024 + i] = bk[i];
    return;
  }
  const int wave = threadIdx.x >> 6, lane = threadIdx.x & 63;
  const int c = b * 4 + wave;
  const bf16_t* row = WoT + (long)c * 1024 + lane * 16;
  const float*  bvp = bv + lane * 16;
  float s = 0.f;
  #pragma unroll
  for (int j = 0; j < 16; ++j) s += bvp[j] * (float)row[j];
  #pragma unroll
  for (int sh = 32; sh > 0; sh >>= 1) s += __shfl_xor(s, sh, 64);
  if (lane == 0) o[2048 + c] = s;
}

// ---------------------------------------------------------------------------
extern "C" void kernel_launch(void* const* d_in, const int* in_sizes, int n_in,
                              void* d_out, int out_size, void* d_ws, size_t ws_size,
                              hipStream_t stream) {
  const float* x  = (const float*)d_in[0];
  const float* Wq = (const float*)d_in[1];
  const float* bq = (const float*)d_in[2];
  const float* Wk = (const float*)d_in[3];
  const float* bk = (const float*)d_in[4];
  const float* Wv = (const float*)d_in[5];
  const float* bv = (const float*)d_in[6];
  const float* Wo = (const float*)d_in[7];
  const float* bo = (const float*)d_in[8];
  float* out = (float*)d_out;

  size_t off = 0;
  auto alloc = [&](size_t bytes) -> void* {
    void* p = (char*)d_ws + off;
    off += (bytes + 255) & ~(size_t)255;
    return p;
  };
  bf16_t* x_b   = (bf16_t*)alloc((size_t)MF * D * 2);          // 16.8 MB
  bf16_t* Wall  = (bf16_t*)alloc((size_t)5 * D * D * 2);       // [WqT|WkT|WvoT|WvN|WoT]
  float*  bqkv  = (float*) alloc((size_t)3 * D * 4);
  uint8_t* q8   = (uint8_t*)alloc((size_t)MF * D);             // 8.4 MB fp8
  uint8_t* k8   = (uint8_t*)alloc((size_t)MF * D);             // 8.4 MB fp8
  bf16_t* vwT_b = (bf16_t*)alloc((size_t)BATCH * D * S * 2);   // [b][D][S]
  bf16_t* probs = (bf16_t*)alloc((size_t)BATCH * S * S * 2);   // 33.5 MB
  float*  part  = (float*) alloc((size_t)MF * 32 * 4);         // 1 MB
  float*  invl  = (float*) alloc((size_t)MF * 4);
  bf16_t* WqkvT = Wall;                       // stacked B for QKV: [3D][D]
  bf16_t* WvoT  = Wall + (size_t)2 * D * D;
  bf16_t* WvN   = Wall + (size_t)3 * D * D;   // Wv natural layout, bf16
  bf16_t* WoT   = Wall + (size_t)4 * D * D;

  // 1. preamble: x -> bf16; weights -> bf16; bias (bvo via WoT, parallel)
  cvt_x<<<dim3((MF * D / 4 + 255) / 256), 256, 0, stream>>>(
      (const float4*)x, (bf16x4*)x_b, MF * D / 4);
  cvt_w_t4<<<dim3(32, 32, 4), 256, 0, stream>>>(Wq, Wk, Wv, Wo, Wall);
  bias_build<<<dim3(260), 256, 0, stream>>>(bq, bk, bv, WoT, bqkv);

  // 2. WvoT = (Wv@Wo)^T folded weight (so PV emits the final output directly)
  gemm_wvo<<<dim3(8, 8), 256, 0, stream>>>(WoT, WvN, WvoT);

  // 3. fused projection: q/k in fp8 e4m3, vw bf16 transposed (XCD-swizzled)
  gemm_qkv<<<dim3(1536), 256, 0, stream>>>(x_b, WqkvT, q8, k8, vwT_b, bqkv);

  // 4. scores (fp8 MFMA) -> exp(./32) bf16 probs + partial row sums
  gemm_sc8<<<dim3(544), 256, 0, stream>>>(q8, k8, probs, part);

  // 5. inv row sums
  reduce_invl<<<dim3(MF / 256), 256, 0, stream>>>(part, invl);

  // 6. out = (P vw) * invl + bo   (final, fp32, causal k-limit, CU-balanced)
  gemm_pv_out<<<dim3(512), 256, 0, stream>>>(probs, vwT_b, out, invl, bo);
}

// Round 4
// 251.418 us; speedup vs baseline: 1.3509x; 1.3509x over previous
//
#include <hip/hip_runtime.h>
#include <stdint.h>

typedef __bf16 bf16_t;
typedef __bf16 bf16x8 __attribute__((ext_vector_type(8)));
typedef __bf16 bf16x4 __attribute__((ext_vector_type(4)));
typedef float  f32x4  __attribute__((ext_vector_type(4)));

#define DEV __device__ __forceinline__

constexpr int S = 2048, D = 1024, BATCH = 4, MF = BATCH * S;

// async global->LDS, 16B per lane. LDS dest is wave-uniform base + lane*16.
DEV void gload16(const void* g, void* l) {
  __builtin_amdgcn_global_load_lds(
      (const __attribute__((address_space(1))) void*)g,
      (__attribute__((address_space(3))) void*)(uint32_t)(uintptr_t)l,
      16, 0, 0);
}

// ---------------------------------------------------------------------------
// bf16 NT GEMM body: C[m][n] = sum_k A[m][k]*B[n][k], fp32 acc.
// Tile 128x128, BK=64, 256 thr (4 waves, 2x2 of 64x64). 16-B chunks
// XOR-swizzled by (row&7) on the GLOBAL source side -> 0 bank conflicts.
// EP: 1 = QKV split: q/k -> fp8 [MF][D], vw transposed bf16 -> vwT[b][D][S]
//     3 = FINAL: out = acc * invl[row] + bo[n], fp32 (PV with folded Wo)
//     4 = plain bf16 out, ldc = D (WvoT precompute)
// NOTE (R3 lesson): with tm on the fast grid axis, default dispatch already
// gives XCD x the tiles tm===x (mod 8) -> per-XCD A footprint 2MB, L2-fit.
// Do NOT remap blockIdx here.
// ---------------------------------------------------------------------------
template<int EP>
DEV void gemm_body(int tm, int tn, int bz,
                   const bf16_t* __restrict__ A, const bf16_t* __restrict__ B,
                   void* __restrict__ C0, void* __restrict__ C1,
                   void* __restrict__ C2, const float* __restrict__ aux,
                   int K, int kmax, bf16_t* ldsA, bf16_t* ldsB)
{
  const int m0 = tm * 128, n0 = tn * 128;
  const int tid  = threadIdx.x;
  const int lane = tid & 63;
  const int wave = tid >> 6;
  const int wm = wave & 1, wn = wave >> 1;
  const int l8r = lane >> 3;                  // row within 8-row staging block
  const int swz = ((lane & 7) ^ (lane >> 3)) * 8;  // swizzled k-chunk (elems)
  const int cl  = lane & 15;                  // fragment m/n index
  const int qd  = lane >> 4;                  // quad -> k-slice
  const int ch0 = ((qd ^ (cl & 7)) * 8);      // swizzled read chunk, kk=0

  f32x4 acc[4][4] = {};

  for (int k0 = 0; k0 < kmax; k0 += 64) {
    #pragma unroll
    for (int t = 0; t < 4; ++t) {
      const int rb = wave * 4 + t;
      gload16(A + (long)(m0 + rb * 8 + l8r) * K + (k0 + swz), &ldsA[rb * 512]);
      gload16(B + (long)(n0 + rb * 8 + l8r) * K + (k0 + swz), &ldsB[rb * 512]);
    }
    __syncthreads();
    #pragma unroll
    for (int kk = 0; kk < 64; kk += 32) {
      bf16x8 af[4], bg[4];
      #pragma unroll
      for (int i = 0; i < 4; ++i)
        af[i] = *(const bf16x8*)&ldsA[(wm * 64 + i * 16 + cl) * 64 + (ch0 ^ kk)];
      #pragma unroll
      for (int j = 0; j < 4; ++j)
        bg[j] = *(const bf16x8*)&ldsB[(wn * 64 + j * 16 + cl) * 64 + (ch0 ^ kk)];
      #pragma unroll
      for (int i = 0; i < 4; ++i)
        #pragma unroll
        for (int j = 0; j < 4; ++j)
          acc[i][j] = __builtin_amdgcn_mfma_f32_16x16x32_bf16(af[i], bg[j], acc[i][j], 0, 0, 0);
    }
    __syncthreads();
  }

  // Epilogues. C/D layout: col = lane&15, row = (lane>>4)*4 + reg.
  #pragma unroll
  for (int i = 0; i < 4; ++i) {
    const int gm0 = m0 + wm * 64 + i * 16 + qd * 4;

    if (EP == 1) {                            // QK (fp8) + VW (bf16) split
      uint8_t* q8 = (uint8_t*)C0;
      uint8_t* k8 = (uint8_t*)C1;
      bf16_t* vwT = (bf16_t*)C2;
      #pragma unroll
      for (int j = 0; j < 4; ++j) {
        const int gn  = n0 + wn * 64 + j * 16 + cl;
        const int sec = gn >> 10, ln = gn & 1023;
        const float bn = aux[gn];
        if (sec == 2) {                       // vw: store transposed, 4x bf16
          const int z = gm0 >> 11, s0 = gm0 & 2047;
          bf16x4 v4;
          #pragma unroll
          for (int r = 0; r < 4; ++r) v4[r] = (bf16_t)(acc[i][j][r] + bn);
          *(bf16x4*)&vwT[((long)z * D + ln) * S + s0] = v4;
        } else {
          uint8_t* dst = (sec == 0) ? q8 : k8;
          #pragma unroll
          for (int r = 0; r < 4; ++r) {
            const float v = acc[i][j][r] + bn;
            const int p = __builtin_amdgcn_cvt_pk_fp8_f32(v, v, 0, false);
            dst[(long)(gm0 + r) * D + ln] = (uint8_t)(p & 0xFF);
          }
        }
      }
    }

    if (EP == 3) {                            // FINAL: fp32 out, invl + bo
      float* out = (float*)C0 + (long)bz * S * D;
      const float* invl = aux + (long)bz * S;
      const float* bo = (const float*)C1;
      float scl[4];
      #pragma unroll
      for (int r = 0; r < 4; ++r) scl[r] = invl[gm0 + r];
      #pragma unroll
      for (int j = 0; j < 4; ++j) {
        const int gn = n0 + wn * 64 + j * 16 + cl;
        const float bn = bo[gn];
        #pragma unroll
        for (int r = 0; r < 4; ++r)
          out[(long)(gm0 + r) * D + gn] = acc[i][j][r] * scl[r] + bn;
      }
    }

    if (EP == 4) {                            // plain bf16 out (Wvo precomp)
      bf16_t* Co = (bf16_t*)C0;
      #pragma unroll
      for (int j = 0; j < 4; ++j) {
        const int gn = n0 + wn * 64 + j * 16 + cl;
        #pragma unroll
        for (int r = 0; r < 4; ++r)
          Co[(long)(gm0 + r) * D + gn] = (bf16_t)acc[i][j][r];
      }
    }
  }
}

// Q/K projection: tn 0..15 (q8, k8 outputs). 1024 blocks = exactly 4/CU.
__global__ __launch_bounds__(256, 4) void gemm_qk(
    const bf16_t* __restrict__ A, const bf16_t* __restrict__ B,
    uint8_t* q8, uint8_t* k8, bf16_t* vwT, const float* __restrict__ bias)
{
  __shared__ __align__(16) bf16_t lA[128 * 64], lB[128 * 64];
  gemm_body<1>(blockIdx.x, blockIdx.y, 0, A, B, q8, k8, vwT, bias,
               1024, 1024, lA, lB);
}

// VW projection: tn 16..23 (vwT output, B rows = WvoT). 512 blocks.
__global__ __launch_bounds__(256, 4) void gemm_vw(
    const bf16_t* __restrict__ A, const bf16_t* __restrict__ B,
    uint8_t* q8, uint8_t* k8, bf16_t* vwT, const float* __restrict__ bias)
{
  __shared__ __align__(16) bf16_t lA[128 * 64], lB[128 * 64];
  gemm_body<1>(blockIdx.x, blockIdx.y + 16, 0, A, B, q8, k8, vwT, bias,
               1024, 1024, lA, lB);
}

// ---------------------------------------------------------------------------
// fp8 scores kernel: probs = exp(q8·k8^T / 32) causal, bf16 + partial sums.
// Same 128x128 tile geometry; LDS rows = 64 fp8 = 64 B. 16-B granules
// XOR-swizzled by (row>>1)&3 (global-source side) -> <=2-way conflicts (free).
// mfma_f32_16x16x32_fp8_fp8: A/B operand = 8 bytes (long), k = quad*8+[0..7].
// 544 blocks, blockIdx%8 = XCD, 2 XCDs/batch, 68-tile triangle halves.
// ---------------------------------------------------------------------------
__global__ __launch_bounds__(256, 4) void gemm_sc8(
    const uint8_t* __restrict__ q8g, const uint8_t* __restrict__ k8g,
    bf16_t* __restrict__ probs_g, float* __restrict__ part)
{
  __shared__ __align__(16) uint8_t lA[128 * 64], lB[128 * 64];
  const int l = blockIdx.x, xcd = l & 7, idx = l >> 3;
  const int bz = xcd >> 1;
  const int t  = (xcd & 1) * 68 + idx;             // triangular index 0..135
  int tm = (int)((sqrtf(8.0f * t + 1.0f) - 1.0f) * 0.5f);
  while ((tm + 1) * (tm + 2) / 2 <= t) ++tm;
  while (tm * (tm + 1) / 2 > t) --tm;
  const int tn = t - tm * (tm + 1) / 2;
  const int m0 = tm * 128, n0 = tn * 128;
  const uint8_t* q8 = q8g + (long)bz * S * D;
  const uint8_t* k8 = k8g + (long)bz * S * D;

  const int tid  = threadIdx.x;
  const int lane = tid & 63;
  const int wave = tid >> 6;
  const int wm = wave & 1, wn = wave >> 1;
  const int srow = lane >> 2;                      // staging row in 16-slab
  const int sgr  = (lane & 3) ^ ((lane >> 3) & 3); // swizzled source granule
  const int cl = lane & 15, qd = lane >> 4;
  const int sfr = (cl >> 1) & 3;                   // frag-read swizzle key
  const int half8 = (qd & 1) * 8;

  f32x4 acc[4][4] = {};

  for (int k0 = 0; k0 < 1024; k0 += 64) {
    #pragma unroll
    for (int tt = 0; tt < 2; ++tt) {
      const int rb = wave * 2 + tt;                // 16-row slab (0..7)
      const int gr = rb * 16 + srow;
      gload16(q8 + (long)(m0 + gr) * 1024 + k0 + sgr * 16, &lA[rb * 1024]);
      gload16(k8 + (long)(n0 + gr) * 1024 + k0 + sgr * 16, &lB[rb * 1024]);
    }
    __syncthreads();
    #pragma unroll
    for (int kk = 0; kk < 2; ++kk) {
      long a[4], b[4];
      const int pg = ((kk << 1) + (qd >> 1)) ^ sfr;
      #pragma unroll
      for (int i = 0; i < 4; ++i)
        a[i] = *(const long*)&lA[(wm * 64 + i * 16 + cl) * 64 + pg * 16 + half8];
      #pragma unroll
      for (int j = 0; j < 4; ++j)
        b[j] = *(const long*)&lB[(wn * 64 + j * 16 + cl) * 64 + pg * 16 + half8];
      #pragma unroll
      for (int i = 0; i < 4; ++i)
        #pragma unroll
        for (int j = 0; j < 4; ++j)
          acc[i][j] = __builtin_amdgcn_mfma_f32_16x16x32_fp8_fp8(a[i], b[j], acc[i][j], 0, 0, 0);
    }
    __syncthreads();
  }

  // epilogue: exp(acc/32) causal -> bf16 probs + partial row sums
  bf16_t* probs = probs_g + (long)bz * S * S;
  #pragma unroll
  for (int i = 0; i < 4; ++i) {
    const int gm0 = m0 + wm * 64 + i * 16 + qd * 4;
    float ls[4] = {0.f, 0.f, 0.f, 0.f};
    #pragma unroll
    for (int j = 0; j < 4; ++j) {
      const int gn = n0 + wn * 64 + j * 16 + cl;
      #pragma unroll
      for (int r = 0; r < 4; ++r) {
        const int gm = gm0 + r;
        const float e = (gn <= gm) ? __expf(acc[i][j][r] * 0.03125f) : 0.0f;
        probs[(long)gm * S + gn] = (bf16_t)e;
        ls[r] += e;
      }
    }
    #pragma unroll
    for (int r = 0; r < 4; ++r) {
      float v = ls[r];
      v += __shfl_xor(v, 1); v += __shfl_xor(v, 2);
      v += __shfl_xor(v, 4); v += __shfl_xor(v, 8);
      if (cl == 0)
        part[((long)bz * S + (gm0 + r)) * 32 + tn * 2 + wn] = v;
    }
  }
}

// Final PV(+folded Wo): 512 blocks, 2 XCDs/batch. Per-CU exact K balance:
// within an XCD (64 blocks on 32 CUs, idx c pairs with c+32), idx<32 take
// long-K m's {15,13,11,9}-half, idx>=32 take {0,2,4,6}+half with matching g
// -> every CU gets exactly 17 k-tiles.
__global__ __launch_bounds__(256, 4) void gemm_pv_out(
    const bf16_t* __restrict__ probs, const bf16_t* __restrict__ vwT,
    float* out, const float* __restrict__ invl, const float* __restrict__ bo)
{
  __shared__ __align__(16) bf16_t lA[128 * 64], lB[128 * 64];
  const int l = blockIdx.x, xcd = l & 7, idx = l >> 3;
  const int bz = xcd >> 1, half = xcd & 1;
  const int g = (idx >> 3) & 3, tn = idx & 7;
  const int tm = (idx < 32) ? (15 - half - 2 * g) : (2 * g + half);
  const int kmax = (tm + 1) * 128;
  gemm_body<3>(tm, tn, bz, probs + (long)bz * S * S, vwT + (long)bz * D * S,
               out, (void*)bo, nullptr, invl, 2048, kmax, lA, lB);
}

// WvoT[c][i] = sum_n Wv[i][n] * Wo[n][c]  (so vw = x @ (Wv@Wo)).
__global__ __launch_bounds__(256, 4) void gemm_wvo(
    const bf16_t* __restrict__ WoT, const bf16_t* __restrict__ WvN,
    bf16_t* WvoT)
{
  __shared__ __align__(16) bf16_t lA[128 * 64], lB[128 * 64];
  gemm_body<4>(blockIdx.x, blockIdx.y, 0, WoT, WvN, WvoT, nullptr, nullptr,
               nullptr, 1024, 1024, lA, lB);
}

// inv_l[row] = 1 / sum(valid partials). Row tile tm has (tm+1)*2 valid entries.
__global__ __launch_bounds__(256) void reduce_invl(
    const float* __restrict__ part, float* __restrict__ invl)
{
  const int r = blockIdx.x * 256 + threadIdx.x;   // 0..MF-1
  const int row = r & (S - 1);
  const int cnt = ((row >> 7) + 1) * 2;
  const float* p = part + (long)r * 32;
  float s = 0.f;
  for (int j = 0; j < cnt; ++j) s += p[j];
  invl[r] = 1.0f / s;
}

// fp32 -> bf16 elementwise (x), 4 elems/thread
__global__ __launch_bounds__(256) void cvt_x(
    const float4* __restrict__ in, bf16x4* __restrict__ out, int n4)
{
  const int i = blockIdx.x * 256 + threadIdx.x;
  if (i >= n4) return;
  float4 f = in[i];
  bf16x4 o;
  o.x = (__bf16)f.x; o.y = (__bf16)f.y; o.z = (__bf16)f.z; o.w = (__bf16)f.w;
  out[i] = o;
}

// Weights -> bf16. z=0: Wq^T -> slot0; z=1: Wk^T -> slot1; z=3: Wo^T -> slot4
// (transposed via LDS). z=2: Wv plain cast (natural [i][n]) -> slot3.
// Slot 2 (WvoT) is filled by gemm_wvo.
__global__ __launch_bounds__(256) void cvt_w_t4(
    const float* __restrict__ W0, const float* __restrict__ W1,
    const float* __restrict__ W2, const float* __restrict__ W3,
    bf16_t* __restrict__ dst)
{
  const int zmap[4] = {0, 1, 3, 4};
  const float* W = (blockIdx.z == 0) ? W0 : (blockIdx.z == 1) ? W1
                 : (blockIdx.z == 2) ? W2 : W3;
  bf16_t* WT = dst + (size_t)zmap[blockIdx.z] * D * D;
  const int bx = blockIdx.x, by = blockIdx.y;
  const int tx = threadIdx.x & 31, ty = threadIdx.x >> 5;  // 32 x 8

  if (blockIdx.z == 2) {                      // Wv: plain cast, no transpose
    #pragma unroll
    for (int dy = 0; dy < 32; dy += 8) {
      const long idx = (long)(by * 32 + ty + dy) * 1024 + bx * 32 + tx;
      WT[idx] = (bf16_t)W[idx];
    }
    return;
  }

  __shared__ float t[32][33];
  #pragma unroll
  for (int dy = 0; dy < 32; dy += 8)
    t[ty + dy][tx] = W[(long)(by * 32 + ty + dy) * 1024 + bx * 32 + tx];
  __syncthreads();
  #pragma unroll
  for (int dy = 0; dy < 32; dy += 8)
    WT[(long)(bx * 32 + ty + dy) * 1024 + by * 32 + tx] = (bf16_t)t[tx][ty + dy];
}

// bias build: blocks 0..255 -> bvo[c] = sum_e bv[e]*WoT[c][e], one wave per
// column (coalesced row read + butterfly). Blocks 256..259 copy bq/bk.
__global__ __launch_bounds__(256) void bias_build(
    const float* __restrict__ bq, const float* __restrict__ bk,
    const float* __restrict__ bv, const bf16_t* __restrict__ WoT,
    float* __restrict__ o)
{
  const int b = blockIdx.x;
  if (b >= 256) {
    const int i = (b - 256) * 256 + threadIdx.x;   // 0..1023
    o[i] = bq[i];
    o[1024 + i] = bk[i];
    return;
  }
  const int wave = threadIdx.x >> 6, lane = threadIdx.x & 63;
  const int c = b * 4 + wave;
  const bf16_t* row = WoT + (long)c * 1024 + lane * 16;
  const float*  bvp = bv + lane * 16;
  float s = 0.f;
  #pragma unroll
  for (int j = 0; j < 16; ++j) s += bvp[j] * (float)row[j];
  #pragma unroll
  for (int sh = 32; sh > 0; sh >>= 1) s += __shfl_xor(s, sh, 64);
  if (lane == 0) o[2048 + c] = s;
}

// ---------------------------------------------------------------------------
extern "C" void kernel_launch(void* const* d_in, const int* in_sizes, int n_in,
                              void* d_out, int out_size, void* d_ws, size_t ws_size,
                              hipStream_t stream) {
  const float* x  = (const float*)d_in[0];
  const float* Wq = (const float*)d_in[1];
  const float* bq = (const float*)d_in[2];
  const float* Wk = (const float*)d_in[3];
  const float* bk = (const float*)d_in[4];
  const float* Wv = (const float*)d_in[5];
  const float* bv = (const float*)d_in[6];
  const float* Wo = (const float*)d_in[7];
  const float* bo = (const float*)d_in[8];
  float* out = (float*)d_out;

  size_t off = 0;
  auto alloc = [&](size_t bytes) -> void* {
    void* p = (char*)d_ws + off;
    off += (bytes + 255) & ~(size_t)255;
    return p;
  };
  bf16_t* x_b   = (bf16_t*)alloc((size_t)MF * D * 2);          // 16.8 MB
  bf16_t* Wall  = (bf16_t*)alloc((size_t)5 * D * D * 2);       // [WqT|WkT|WvoT|WvN|WoT]
  float*  bqkv  = (float*) alloc((size_t)3 * D * 4);
  uint8_t* q8   = (uint8_t*)alloc((size_t)MF * D);             // 8.4 MB fp8
  uint8_t* k8   = (uint8_t*)alloc((size_t)MF * D);             // 8.4 MB fp8
  bf16_t* vwT_b = (bf16_t*)alloc((size_t)BATCH * D * S * 2);   // [b][D][S]
  bf16_t* probs = (bf16_t*)alloc((size_t)BATCH * S * S * 2);   // 33.5 MB
  float*  part  = (float*) alloc((size_t)MF * 32 * 4);         // 1 MB
  float*  invl  = (float*) alloc((size_t)MF * 4);
  bf16_t* WqkvT = Wall;                       // stacked B for QKV: [3D][D]
  bf16_t* WvoT  = Wall + (size_t)2 * D * D;
  bf16_t* WvN   = Wall + (size_t)3 * D * D;   // Wv natural layout, bf16
  bf16_t* WoT   = Wall + (size_t)4 * D * D;

  // 1. preamble: x -> bf16; weights -> bf16; bias (bvo via WoT, parallel)
  cvt_x<<<dim3((MF * D / 4 + 255) / 256), 256, 0, stream>>>(
      (const float4*)x, (bf16x4*)x_b, MF * D / 4);
  cvt_w_t4<<<dim3(32, 32, 4), 256, 0, stream>>>(Wq, Wk, Wv, Wo, Wall);
  bias_build<<<dim3(260), 256, 0, stream>>>(bq, bk, bv, WoT, bqkv);

  // 2. WvoT = (Wv@Wo)^T folded weight (so PV emits the final output directly)
  gemm_wvo<<<dim3(8, 8), 256, 0, stream>>>(WoT, WvN, WvoT);

  // 3. fused projection, split: q/k (fp8) then vw (bf16 transposed)
  gemm_qk<<<dim3(64, 16), 256, 0, stream>>>(x_b, WqkvT, q8, k8, vwT_b, bqkv);
  gemm_vw<<<dim3(64, 8), 256, 0, stream>>>(x_b, WqkvT, q8, k8, vwT_b, bqkv);

  // 4. scores (fp8 MFMA) -> exp(./32) bf16 probs + partial row sums
  gemm_sc8<<<dim3(544), 256, 0, stream>>>(q8, k8, probs, part);

  // 5. inv row sums
  reduce_invl<<<dim3(MF / 256), 256, 0, stream>>>(part, invl);

  // 6. out = (P vw) * invl + bo   (final, fp32, causal k-limit, CU-balanced)
  gemm_pv_out<<<dim3(512), 256, 0, stream>>>(probs, vwT_b, out, invl, bo);
}

// Round 6
// 250.590 us; speedup vs baseline: 1.3554x; 1.0033x over previous
//
#include <hip/hip_runtime.h>
#include <stdint.h>

typedef __bf16 bf16_t;
typedef __bf16 bf16x8 __attribute__((ext_vector_type(8)));
typedef __bf16 bf16x4 __attribute__((ext_vector_type(4)));
typedef float  f32x4  __attribute__((ext_vector_type(4)));

#define DEV __device__ __forceinline__

constexpr int S = 2048, D = 1024, BATCH = 4, MF = BATCH * S;

// async global->LDS, 16B per lane. LDS dest is wave-uniform base + lane*16.
DEV void gload16(const void* g, void* l) {
  __builtin_amdgcn_global_load_lds(
      (const __attribute__((address_space(1))) void*)g,
      (__attribute__((address_space(3))) void*)(uint32_t)(uintptr_t)l,
      16, 0, 0);
}

// ---------------------------------------------------------------------------
// bf16 NT GEMM body: C[m][n] = sum_k A[m][k]*B[n][k], fp32 acc.
// Tile 128x128, BK=64, 256 thr (4 waves, 2x2 of 64x64). 16-B chunks
// XOR-swizzled by (row&7) on the GLOBAL source side -> 0 bank conflicts.
// EP: 1 = QKV split: q/k -> fp8 [MF][D], vw transposed bf16 -> vwT[b][D][S]
//     4 = plain bf16 out, ldc = D (WvoT precompute)
//     5 = FINAL: out = acc * invl_lds[local row] + bo[n], fp32 (PV+folded Wo)
// NOTE (R3 lesson): with tm on the fast grid axis, default dispatch already
// gives XCD x the tiles tm===x (mod 8) -> per-XCD A footprint 2MB, L2-fit.
// Do NOT remap blockIdx here.
// ---------------------------------------------------------------------------
template<int EP>
DEV void gemm_body(int tm, int tn, int bz,
                   const bf16_t* __restrict__ A, const bf16_t* __restrict__ B,
                   void* __restrict__ C0, void* __restrict__ C1,
                   void* __restrict__ C2, const float* __restrict__ aux,
                   int K, int kmax, bf16_t* ldsA, bf16_t* ldsB)
{
  const int m0 = tm * 128, n0 = tn * 128;
  const int tid  = threadIdx.x;
  const int lane = tid & 63;
  const int wave = tid >> 6;
  const int wm = wave & 1, wn = wave >> 1;
  const int l8r = lane >> 3;                  // row within 8-row staging block
  const int swz = ((lane & 7) ^ (lane >> 3)) * 8;  // swizzled k-chunk (elems)
  const int cl  = lane & 15;                  // fragment m/n index
  const int qd  = lane >> 4;                  // quad -> k-slice
  const int ch0 = ((qd ^ (cl & 7)) * 8);      // swizzled read chunk, kk=0

  f32x4 acc[4][4] = {};

  for (int k0 = 0; k0 < kmax; k0 += 64) {
    #pragma unroll
    for (int t = 0; t < 4; ++t) {
      const int rb = wave * 4 + t;
      gload16(A + (long)(m0 + rb * 8 + l8r) * K + (k0 + swz), &ldsA[rb * 512]);
      gload16(B + (long)(n0 + rb * 8 + l8r) * K + (k0 + swz), &ldsB[rb * 512]);
    }
    __syncthreads();
    #pragma unroll
    for (int kk = 0; kk < 64; kk += 32) {
      bf16x8 af[4], bg[4];
      #pragma unroll
      for (int i = 0; i < 4; ++i)
        af[i] = *(const bf16x8*)&ldsA[(wm * 64 + i * 16 + cl) * 64 + (ch0 ^ kk)];
      #pragma unroll
      for (int j = 0; j < 4; ++j)
        bg[j] = *(const bf16x8*)&ldsB[(wn * 64 + j * 16 + cl) * 64 + (ch0 ^ kk)];
      #pragma unroll
      for (int i = 0; i < 4; ++i)
        #pragma unroll
        for (int j = 0; j < 4; ++j)
          acc[i][j] = __builtin_amdgcn_mfma_f32_16x16x32_bf16(af[i], bg[j], acc[i][j], 0, 0, 0);
    }
    __syncthreads();
  }

  // Epilogues. C/D layout: col = lane&15, row = (lane>>4)*4 + reg.
  #pragma unroll
  for (int i = 0; i < 4; ++i) {
    const int gm0 = m0 + wm * 64 + i * 16 + qd * 4;

    if (EP == 1) {                            // QK (fp8) + VW (bf16) split
      uint8_t* q8 = (uint8_t*)C0;
      uint8_t* k8 = (uint8_t*)C1;
      bf16_t* vwT = (bf16_t*)C2;
      #pragma unroll
      for (int j = 0; j < 4; ++j) {
        const int gn  = n0 + wn * 64 + j * 16 + cl;
        const int sec = gn >> 10, ln = gn & 1023;
        const float bn = aux[gn];
        if (sec == 2) {                       // vw: store transposed, 4x bf16
          const int z = gm0 >> 11, s0 = gm0 & 2047;
          bf16x4 v4;
          #pragma unroll
          for (int r = 0; r < 4; ++r) v4[r] = (bf16_t)(acc[i][j][r] + bn);
          *(bf16x4*)&vwT[((long)z * D + ln) * S + s0] = v4;
        } else {
          uint8_t* dst = (sec == 0) ? q8 : k8;
          #pragma unroll
          for (int r = 0; r < 4; ++r) {
            const float v = acc[i][j][r] + bn;
            const int p = __builtin_amdgcn_cvt_pk_fp8_f32(v, v, 0, false);
            dst[(long)(gm0 + r) * D + ln] = (uint8_t)(p & 0xFF);
          }
        }
      }
    }

    if (EP == 5) {                            // FINAL: fp32 out, LDS invl + bo
      float* out = (float*)C0 + (long)bz * S * D;
      const float* bo = (const float*)C1;
      const float* invl_l = aux;              // LDS, indexed by tile-local row
      float scl[4];
      #pragma unroll
      for (int r = 0; r < 4; ++r) scl[r] = invl_l[wm * 64 + i * 16 + qd * 4 + r];
      #pragma unroll
      for (int j = 0; j < 4; ++j) {
        const int gn = n0 + wn * 64 + j * 16 + cl;
        const float bn = bo[gn];
        #pragma unroll
        for (int r = 0; r < 4; ++r)
          out[(long)(gm0 + r) * D + gn] = acc[i][j][r] * scl[r] + bn;
      }
    }

    if (EP == 4) {                            // plain bf16 out (Wvo precomp)
      bf16_t* Co = (bf16_t*)C0;
      #pragma unroll
      for (int j = 0; j < 4; ++j) {
        const int gn = n0 + wn * 64 + j * 16 + cl;
        #pragma unroll
        for (int r = 0; r < 4; ++r)
          Co[(long)(gm0 + r) * D + gn] = (bf16_t)acc[i][j][r];
      }
    }
  }
}

// QK+VW projection: plain grid (64, 24) — default dispatch is already
// XCD-optimal (see NOTE above).
__global__ __launch_bounds__(256, 4) void gemm_qkv(
    const bf16_t* __restrict__ A, const bf16_t* __restrict__ B,
    uint8_t* q8, uint8_t* k8, bf16_t* vwT, const float* __restrict__ bias)
{
  __shared__ __align__(16) bf16_t lA[128 * 64], lB[128 * 64];
  gemm_body<1>(blockIdx.x, blockIdx.y, 0, A, B, q8, k8, vwT, bias,
               1024, 1024, lA, lB);
}

// ---------------------------------------------------------------------------
// fp8 scores kernel: probs = exp(q8·k8^T / 32) causal, bf16 + partial sums.
// R4: 64x128 tiles (was 128x128) -> 1088 blocks = 4.25/CU (was 2.1/CU) for
// latency hiding. 4 waves arranged 1M x 4N: wave wn covers 64 rows x 32 cols.
// LDS rows = 64 fp8 = 64 B; 16-B granules XOR-swizzled by (row>>1)&3
// (global-source side). A/B fragment rows stay ==cl (mod 16) so the same
// read swizzle key sfr=(cl>>1)&3 applies.
// Tile enum per batch: 272 tiles; row-tile r64 (64 rows) has floor(r64/2)+1
// k-tiles. Cumulative C(2a)=a^2+a, C(2a+1)=(a+1)^2. 2 XCDs/batch, 136 each.
// Partials: part[row][tn*4+wn], stride 64.
// ---------------------------------------------------------------------------
__global__ __launch_bounds__(256, 6) void gemm_sc8(
    const uint8_t* __restrict__ q8g, const uint8_t* __restrict__ k8g,
    bf16_t* __restrict__ probs_g, float* __restrict__ part)
{
  __shared__ __align__(16) uint8_t lA[64 * 64], lB[128 * 64];
  const int l = blockIdx.x, xcd = l & 7, idx = l >> 3;
  const int bz = xcd >> 1;
  const int t  = (xcd & 1) * 136 + idx;            // 0..271 per batch
  int a0 = (int)((sqrtf(4.0f * t + 1.0f) - 1.0f) * 0.5f);
  while ((a0 + 1) * (a0 + 2) <= t) ++a0;           // largest a: a(a+1) <= t
  while (a0 * (a0 + 1) > t) --a0;
  int r64, tn;
  if (t >= (a0 + 1) * (a0 + 1)) { r64 = 2 * a0 + 1; tn = t - (a0 + 1) * (a0 + 1); }
  else                          { r64 = 2 * a0;     tn = t - a0 * (a0 + 1); }
  const int m0 = r64 * 64, n0 = tn * 128;
  const uint8_t* q8 = q8g + (long)bz * S * D;
  const uint8_t* k8 = k8g + (long)bz * S * D;

  const int tid  = threadIdx.x;
  const int lane = tid & 63;
  const int wn   = tid >> 6;                       // wave = n-group 0..3
  const int srow = lane >> 2;                      // staging row in 16-slab
  const int sgr  = (lane & 3) ^ ((lane >> 3) & 3); // swizzled source granule
  const int cl = lane & 15, qd = lane >> 4;
  const int sfr = (cl >> 1) & 3;                   // frag-read swizzle key
  const int half8 = (qd & 1) * 8;

  f32x4 acc[4][2] = {};

  for (int k0 = 0; k0 < 1024; k0 += 64) {
    gload16(q8 + (long)(m0 + wn * 16 + srow) * 1024 + k0 + sgr * 16,
            &lA[wn * 1024]);
    #pragma unroll
    for (int tt = 0; tt < 2; ++tt) {
      const int rb = wn * 2 + tt;                  // 16-row slab (0..7)
      gload16(k8 + (long)(n0 + rb * 16 + srow) * 1024 + k0 + sgr * 16,
              &lB[rb * 1024]);
    }
    __syncthreads();
    #pragma unroll
    for (int kk = 0; kk < 2; ++kk) {
      long av[4], bv[2];
      const int pg = ((kk << 1) + (qd >> 1)) ^ sfr;
      #pragma unroll
      for (int i = 0; i < 4; ++i)
        av[i] = *(const long*)&lA[(i * 16 + cl) * 64 + pg * 16 + half8];
      #pragma unroll
      for (int j = 0; j < 2; ++j)
        bv[j] = *(const long*)&lB[(wn * 32 + j * 16 + cl) * 64 + pg * 16 + half8];
      #pragma unroll
      for (int i = 0; i < 4; ++i)
        #pragma unroll
        for (int j = 0; j < 2; ++j)
          acc[i][j] = __builtin_amdgcn_mfma_f32_16x16x32_fp8_fp8(av[i], bv[j], acc[i][j], 0, 0, 0);
    }
    __syncthreads();
  }

  // epilogue: exp(acc/32) causal -> bf16 probs + partial row sums
  bf16_t* probs = probs_g + (long)bz * S * S;
  #pragma unroll
  for (int i = 0; i < 4; ++i) {
    const int gm0 = m0 + i * 16 + qd * 4;
    float ls[4] = {0.f, 0.f, 0.f, 0.f};
    #pragma unroll
    for (int j = 0; j < 2; ++j) {
      const int gn = n0 + wn * 32 + j * 16 + cl;
      #pragma unroll
      for (int r = 0; r < 4; ++r) {
        const int gm = gm0 + r;
        const float e = (gn <= gm) ? __expf(acc[i][j][r] * 0.03125f) : 0.0f;
        probs[(long)gm * S + gn] = (bf16_t)e;
        ls[r] += e;
      }
    }
    #pragma unroll
    for (int r = 0; r < 4; ++r) {
      float v = ls[r];
      v += __shfl_xor(v, 1); v += __shfl_xor(v, 2);
      v += __shfl_xor(v, 4); v += __shfl_xor(v, 8);
      if (cl == 0)
        part[((long)bz * S + (gm0 + r)) * 64 + tn * 4 + wn] = v;
    }
  }
}

// Final PV(+folded Wo): 512 blocks, 2 XCDs/batch. Per-CU exact K balance:
// within an XCD (64 blocks on 32 CUs, idx c pairs with c+32), idx<32 take
// long-K m's {15,13,11,9}-half, idx>=32 take {0,2,4,6}+half with matching g
// -> every CU gets exactly 17 k-tiles.
// R4: computes inv row sums in the prologue (folds reduce_invl kernel).
__global__ __launch_bounds__(256, 4) void gemm_pv_out(
    const bf16_t* __restrict__ probs, const bf16_t* __restrict__ vwT,
    float* out, const float* __restrict__ part, const float* __restrict__ bo)
{
  __shared__ __align__(16) bf16_t lA[128 * 64], lB[128 * 64];
  __shared__ float invl_s[128];
  const int l = blockIdx.x, xcd = l & 7, idx = l >> 3;
  const int bz = xcd >> 1, half = xcd & 1;
  const int g = (idx >> 3) & 3, tn = idx & 7;
  const int tm = (idx < 32) ? (15 - half - 2 * g) : (2 * g + half);
  const int kmax = (tm + 1) * 128;

  if (threadIdx.x < 128) {                   // invl for this tile's 128 rows
    const int row = tm * 128 + threadIdx.x;
    const int cnt = (tm + 1) * 4;            // valid partials (stride-64 slab)
    const float* p = part + ((long)bz * S + row) * 64;
    float s = 0.f;
    for (int j = 0; j < cnt; ++j) s += p[j];
    invl_s[threadIdx.x] = 1.0f / s;
  }
  __syncthreads();

  gemm_body<5>(tm, tn, bz, probs + (long)bz * S * S, vwT + (long)bz * D * S,
               out, (void*)bo, nullptr, invl_s, 2048, kmax, lA, lB);
}

// WvoT[c][i] = sum_n Wv[i][n] * Wo[n][c]  (so vw = x @ (Wv@Wo)).
__global__ __launch_bounds__(256, 4) void gemm_wvo(
    const bf16_t* __restrict__ WoT, const bf16_t* __restrict__ WvN,
    bf16_t* WvoT)
{
  __shared__ __align__(16) bf16_t lA[128 * 64], lB[128 * 64];
  gemm_body<4>(blockIdx.x, blockIdx.y, 0, WoT, WvN, WvoT, nullptr, nullptr,
               nullptr, 1024, 1024, lA, lB);
}

// fp32 -> bf16 elementwise (x), 4 elems/thread
__global__ __launch_bounds__(256) void cvt_x(
    const float4* __restrict__ in, bf16x4* __restrict__ out, int n4)
{
  const int i = blockIdx.x * 256 + threadIdx.x;
  if (i >= n4) return;
  float4 f = in[i];
  bf16x4 o;
  o.x = (__bf16)f.x; o.y = (__bf16)f.y; o.z = (__bf16)f.z; o.w = (__bf16)f.w;
  out[i] = o;
}

// Weights -> bf16. z=0: Wq^T -> slot0; z=1: Wk^T -> slot1; z=3: Wo^T -> slot4
// (transposed via LDS). z=2: Wv plain cast (natural [i][n]) -> slot3.
// Slot 2 (WvoT) is filled by gemm_wvo.
__global__ __launch_bounds__(256) void cvt_w_t4(
    const float* __restrict__ W0, const float* __restrict__ W1,
    const float* __restrict__ W2, const float* __restrict__ W3,
    bf16_t* __restrict__ dst)
{
  const int zmap[4] = {0, 1, 3, 4};
  const float* W = (blockIdx.z == 0) ? W0 : (blockIdx.z == 1) ? W1
                 : (blockIdx.z == 2) ? W2 : W3;
  bf16_t* WT = dst + (size_t)zmap[blockIdx.z] * D * D;
  const int bx = blockIdx.x, by = blockIdx.y;
  const int tx = threadIdx.x & 31, ty = threadIdx.x >> 5;  // 32 x 8

  if (blockIdx.z == 2) {                      // Wv: plain cast, no transpose
    #pragma unroll
    for (int dy = 0; dy < 32; dy += 8) {
      const long idx = (long)(by * 32 + ty + dy) * 1024 + bx * 32 + tx;
      WT[idx] = (bf16_t)W[idx];
    }
    return;
  }

  __shared__ float t[32][33];
  #pragma unroll
  for (int dy = 0; dy < 32; dy += 8)
    t[ty + dy][tx] = W[(long)(by * 32 + ty + dy) * 1024 + bx * 32 + tx];
  __syncthreads();
  #pragma unroll
  for (int dy = 0; dy < 32; dy += 8)
    WT[(long)(bx * 32 + ty + dy) * 1024 + by * 32 + tx] = (bf16_t)t[tx][ty + dy];
}

// bias build: blocks 0..255 -> bvo[c] = sum_e bv[e]*WoT[c][e], one wave per
// column (coalesced row read + butterfly). Blocks 256..259 copy bq/bk.
__global__ __launch_bounds__(256) void bias_build(
    const float* __restrict__ bq, const float* __restrict__ bk,
    const float* __restrict__ bv, const bf16_t* __restrict__ WoT,
    float* __restrict__ o)
{
  const int b = blockIdx.x;
  if (b >= 256) {
    const int i = (b - 256) * 256 + threadIdx.x;   // 0..1023
    o[i] = bq[i];
    o[1024 + i] = bk[i];
    return;
  }
  const int wave = threadIdx.x >> 6, lane = threadIdx.x & 63;
  const int c = b * 4 + wave;
  const bf16_t* row = WoT + (long)c * 1024 + lane * 16;
  const float*  bvp = bv + lane * 16;
  float s = 0.f;
  #pragma unroll
  for (int j = 0; j < 16; ++j) s += bvp[j] * (float)row[j];
  #pragma unroll
  for (int sh = 32; sh > 0; sh >>= 1) s += __shfl_xor(s, sh, 64);
  if (lane == 0) o[2048 + c] = s;
}

// ---------------------------------------------------------------------------
extern "C" void kernel_launch(void* const* d_in, const int* in_sizes, int n_in,
                              void* d_out, int out_size, void* d_ws, size_t ws_size,
                              hipStream_t stream) {
  const float* x  = (const float*)d_in[0];
  const float* Wq = (const float*)d_in[1];
  const float* bq = (const float*)d_in[2];
  const float* Wk = (const float*)d_in[3];
  const float* bk = (const float*)d_in[4];
  const float* Wv = (const float*)d_in[5];
  const float* bv = (const float*)d_in[6];
  const float* Wo = (const float*)d_in[7];
  const float* bo = (const float*)d_in[8];
  float* out = (float*)d_out;

  size_t off = 0;
  auto alloc = [&](size_t bytes) -> void* {
    void* p = (char*)d_ws + off;
    off += (bytes + 255) & ~(size_t)255;
    return p;
  };
  bf16_t* x_b   = (bf16_t*)alloc((size_t)MF * D * 2);          // 16.8 MB
  bf16_t* Wall  = (bf16_t*)alloc((size_t)5 * D * D * 2);       // [WqT|WkT|WvoT|WvN|WoT]
  float*  bqkv  = (float*) alloc((size_t)3 * D * 4);
  uint8_t* q8   = (uint8_t*)alloc((size_t)MF * D);             // 8.4 MB fp8
  uint8_t* k8   = (uint8_t*)alloc((size_t)MF * D);             // 8.4 MB fp8
  bf16_t* vwT_b = (bf16_t*)alloc((size_t)BATCH * D * S * 2);   // [b][D][S]
  bf16_t* probs = (bf16_t*)alloc((size_t)BATCH * S * S * 2);   // 33.5 MB
  float*  part  = (float*) alloc((size_t)MF * 64 * 4);         // 2 MB
  bf16_t* WqkvT = Wall;                       // stacked B for QKV: [3D][D]
  bf16_t* WvoT  = Wall + (size_t)2 * D * D;
  bf16_t* WvN   = Wall + (size_t)3 * D * D;   // Wv natural layout, bf16
  bf16_t* WoT   = Wall + (size_t)4 * D * D;

  // 1. preamble: x -> bf16; weights -> bf16; bias (bvo via WoT, parallel)
  cvt_x<<<dim3((MF * D / 4 + 255) / 256), 256, 0, stream>>>(
      (const float4*)x, (bf16x4*)x_b, MF * D / 4);
  cvt_w_t4<<<dim3(32, 32, 4), 256, 0, stream>>>(Wq, Wk, Wv, Wo, Wall);
  bias_build<<<dim3(260), 256, 0, stream>>>(bq, bk, bv, WoT, bqkv);

  // 2. WvoT = (Wv@Wo)^T folded weight (so PV emits the final output directly)
  gemm_wvo<<<dim3(8, 8), 256, 0, stream>>>(WoT, WvN, WvoT);

  // 3. fused projection: q/k in fp8 e4m3, vw bf16 transposed
  gemm_qkv<<<dim3(64, 24), 256, 0, stream>>>(x_b, WqkvT, q8, k8, vwT_b, bqkv);

  // 4. scores (fp8 MFMA, 64x128 tiles) -> exp(./32) bf16 probs + partials
  gemm_sc8<<<dim3(1088), 256, 0, stream>>>(q8, k8, probs, part);

  // 5. out = (P vw) * invl + bo  (final, fp32; invl computed in prologue)
  gemm_pv_out<<<dim3(512), 256, 0, stream>>>(probs, vwT_b, out, part, bo);
}

// Round 7
// 243.470 us; speedup vs baseline: 1.3950x; 1.0292x over previous
//
#include <hip/hip_runtime.h>
#include <stdint.h>

typedef __bf16 bf16_t;
typedef __bf16 bf16x8 __attribute__((ext_vector_type(8)));
typedef __bf16 bf16x4 __attribute__((ext_vector_type(4)));
typedef float  f32x4  __attribute__((ext_vector_type(4)));

#define DEV __device__ __forceinline__

constexpr int S = 2048, D = 1024, BATCH = 4, MF = BATCH * S;

// async global->LDS, 16B per lane. LDS dest is wave-uniform base + lane*16.
DEV void gload16(const void* g, void* l) {
  __builtin_amdgcn_global_load_lds(
      (const __attribute__((address_space(1))) void*)g,
      (__attribute__((address_space(3))) void*)(uint32_t)(uintptr_t)l,
      16, 0, 0);
}

// ---------------------------------------------------------------------------
// bf16 NT GEMM body: C[m][n] = sum_k A[m][k]*B[n][k], fp32 acc.
// Tile 128x128, 256 thr (4 waves, 2x2 of 64x64). 16-B chunks XOR-swizzled
// by (row&7) on the GLOBAL source side -> 0 bank conflicts.
// NSUB = 64-col sub-tiles per K-step (BK = 64*NSUB). NSUB=2 doubles
// MFMA-per-barrier for block-count-capped kernels (pv: 2 blocks/CU) at no
// occupancy cost; keep NSUB=1 where 4 blocks/CU are resident (qkv) per m132.
// K-accumulation order is identical for both (strictly increasing k).
// EP: 1 = QKV split: q/k -> fp8 [MF][D], vw transposed bf16 -> vwT[b][D][S]
//     4 = plain bf16 out, ldc = D (WvoT precompute)
//     5 = FINAL: out = acc * invl_lds[local row] + bo[n], fp32 (PV+folded Wo)
// NOTE (R3 lesson): with tm on the fast grid axis, default dispatch already
// gives XCD x the tiles tm===x (mod 8) -> per-XCD A footprint L2-fits.
// Do NOT remap blockIdx.
// ---------------------------------------------------------------------------
template<int EP, int NSUB>
DEV void gemm_body(int tm, int tn, int bz,
                   const bf16_t* __restrict__ A, const bf16_t* __restrict__ B,
                   void* __restrict__ C0, void* __restrict__ C1,
                   void* __restrict__ C2, const float* __restrict__ aux,
                   int K, int kmax, bf16_t* ldsA, bf16_t* ldsB)
{
  const int m0 = tm * 128, n0 = tn * 128;
  const int tid  = threadIdx.x;
  const int lane = tid & 63;
  const int wave = tid >> 6;
  const int wm = wave & 1, wn = wave >> 1;
  const int l8r = lane >> 3;                  // row within 8-row staging block
  const int swz = ((lane & 7) ^ (lane >> 3)) * 8;  // swizzled k-chunk (elems)
  const int cl  = lane & 15;                  // fragment m/n index
  const int qd  = lane >> 4;                  // quad -> k-slice
  const int ch0 = ((qd ^ (cl & 7)) * 8);      // swizzled read chunk, kk=0

  f32x4 acc[4][4] = {};

  for (int k0 = 0; k0 < kmax; k0 += 64 * NSUB) {
    #pragma unroll
    for (int h = 0; h < NSUB; ++h) {
      #pragma unroll
      for (int t = 0; t < 4; ++t) {
        const int rb = wave * 4 + t;
        gload16(A + (long)(m0 + rb * 8 + l8r) * K + (k0 + h * 64 + swz),
                &ldsA[h * 8192 + rb * 512]);
        gload16(B + (long)(n0 + rb * 8 + l8r) * K + (k0 + h * 64 + swz),
                &ldsB[h * 8192 + rb * 512]);
      }
    }
    __syncthreads();
    #pragma unroll
    for (int h = 0; h < NSUB; ++h) {
      #pragma unroll
      for (int kk = 0; kk < 64; kk += 32) {
        bf16x8 af[4], bg[4];
        #pragma unroll
        for (int i = 0; i < 4; ++i)
          af[i] = *(const bf16x8*)&ldsA[h * 8192 + (wm * 64 + i * 16 + cl) * 64 + (ch0 ^ kk)];
        #pragma unroll
        for (int j = 0; j < 4; ++j)
          bg[j] = *(const bf16x8*)&ldsB[h * 8192 + (wn * 64 + j * 16 + cl) * 64 + (ch0 ^ kk)];
        #pragma unroll
        for (int i = 0; i < 4; ++i)
          #pragma unroll
          for (int j = 0; j < 4; ++j)
            acc[i][j] = __builtin_amdgcn_mfma_f32_16x16x32_bf16(af[i], bg[j], acc[i][j], 0, 0, 0);
      }
    }
    __syncthreads();
  }

  // Epilogues. C/D layout: col = lane&15, row = (lane>>4)*4 + reg.
  #pragma unroll
  for (int i = 0; i < 4; ++i) {
    const int gm0 = m0 + wm * 64 + i * 16 + qd * 4;

    if (EP == 1) {                            // QK (fp8) + VW (bf16) split
      uint8_t* q8 = (uint8_t*)C0;
      uint8_t* k8 = (uint8_t*)C1;
      bf16_t* vwT = (bf16_t*)C2;
      #pragma unroll
      for (int j = 0; j < 4; ++j) {
        const int gn  = n0 + wn * 64 + j * 16 + cl;
        const int sec = gn >> 10, ln = gn & 1023;
        const float bn = aux[gn];
        if (sec == 2) {                       // vw: store transposed, 4x bf16
          const int z = gm0 >> 11, s0 = gm0 & 2047;
          bf16x4 v4;
          #pragma unroll
          for (int r = 0; r < 4; ++r) v4[r] = (bf16_t)(acc[i][j][r] + bn);
          *(bf16x4*)&vwT[((long)z * D + ln) * S + s0] = v4;
        } else {
          uint8_t* dst = (sec == 0) ? q8 : k8;
          #pragma unroll
          for (int r = 0; r < 4; ++r) {
            const float v = acc[i][j][r] + bn;
            const int p = __builtin_amdgcn_cvt_pk_fp8_f32(v, v, 0, false);
            dst[(long)(gm0 + r) * D + ln] = (uint8_t)(p & 0xFF);
          }
        }
      }
    }

    if (EP == 5) {                            // FINAL: fp32 out, LDS invl + bo
      float* out = (float*)C0 + (long)bz * S * D;
      const float* bo = (const float*)C1;
      const float* invl_l = aux;              // LDS, indexed by tile-local row
      float scl[4];
      #pragma unroll
      for (int r = 0; r < 4; ++r) scl[r] = invl_l[wm * 64 + i * 16 + qd * 4 + r];
      #pragma unroll
      for (int j = 0; j < 4; ++j) {
        const int gn = n0 + wn * 64 + j * 16 + cl;
        const float bn = bo[gn];
        #pragma unroll
        for (int r = 0; r < 4; ++r)
          out[(long)(gm0 + r) * D + gn] = acc[i][j][r] * scl[r] + bn;
      }
    }

    if (EP == 4) {                            // plain bf16 out (Wvo precomp)
      bf16_t* Co = (bf16_t*)C0;
      #pragma unroll
      for (int j = 0; j < 4; ++j) {
        const int gn = n0 + wn * 64 + j * 16 + cl;
        #pragma unroll
        for (int r = 0; r < 4; ++r)
          Co[(long)(gm0 + r) * D + gn] = (bf16_t)acc[i][j][r];
      }
    }
  }
}

// QK+VW projection: plain grid (64, 24), NSUB=1 (4 blocks/CU resident; BK=128
// would cut to 2 -> m132 regression regime).
__global__ __launch_bounds__(256, 4) void gemm_qkv(
    const bf16_t* __restrict__ A, const bf16_t* __restrict__ B,
    uint8_t* q8, uint8_t* k8, bf16_t* vwT, const float* __restrict__ bias)
{
  __shared__ __align__(16) bf16_t lA[128 * 64], lB[128 * 64];
  gemm_body<1, 1>(blockIdx.x, blockIdx.y, 0, A, B, q8, k8, vwT, bias,
                  1024, 1024, lA, lB);
}

// ---------------------------------------------------------------------------
// fp8 scores kernel (R0 128x128 geometry + BK=128 sub-tiles):
// probs = exp(q8·k8^T / 32) causal, bf16 + partial sums.
// LDS rows = 64 fp8 = 64 B per sub-tile; 16-B granules XOR-swizzled by
// (row>>1)&3 (global-source side) -> <=2-way conflicts (free).
// 544 blocks (2.1/CU, block-count-capped) -> BK=128 doubles MFMA-per-barrier
// (64/wave) at no occupancy cost. 32 KB LDS. 2 XCDs/batch, 68-tile halves.
// ---------------------------------------------------------------------------
__global__ __launch_bounds__(256, 4) void gemm_sc8(
    const uint8_t* __restrict__ q8g, const uint8_t* __restrict__ k8g,
    bf16_t* __restrict__ probs_g, float* __restrict__ part)
{
  __shared__ __align__(16) uint8_t lA[2][128 * 64], lB[2][128 * 64];
  const int l = blockIdx.x, xcd = l & 7, idx = l >> 3;
  const int bz = xcd >> 1;
  const int t  = (xcd & 1) * 68 + idx;             // triangular index 0..135
  int tm = (int)((sqrtf(8.0f * t + 1.0f) - 1.0f) * 0.5f);
  while ((tm + 1) * (tm + 2) / 2 <= t) ++tm;
  while (tm * (tm + 1) / 2 > t) --tm;
  const int tn = t - tm * (tm + 1) / 2;
  const int m0 = tm * 128, n0 = tn * 128;
  const uint8_t* q8 = q8g + (long)bz * S * D;
  const uint8_t* k8 = k8g + (long)bz * S * D;

  const int tid  = threadIdx.x;
  const int lane = tid & 63;
  const int wave = tid >> 6;
  const int wm = wave & 1, wn = wave >> 1;
  const int srow = lane >> 2;                      // staging row in 16-slab
  const int sgr  = (lane & 3) ^ ((lane >> 3) & 3); // swizzled source granule
  const int cl = lane & 15, qd = lane >> 4;
  const int sfr = (cl >> 1) & 3;                   // frag-read swizzle key
  const int half8 = (qd & 1) * 8;

  f32x4 acc[4][4] = {};

  for (int k0 = 0; k0 < 1024; k0 += 128) {
    #pragma unroll
    for (int h = 0; h < 2; ++h) {
      #pragma unroll
      for (int tt = 0; tt < 2; ++tt) {
        const int rb = wave * 2 + tt;              // 16-row slab (0..7)
        const int gr = rb * 16 + srow;
        gload16(q8 + (long)(m0 + gr) * 1024 + k0 + h * 64 + sgr * 16,
                &lA[h][rb * 1024]);
        gload16(k8 + (long)(n0 + gr) * 1024 + k0 + h * 64 + sgr * 16,
                &lB[h][rb * 1024]);
      }
    }
    __syncthreads();
    #pragma unroll
    for (int h = 0; h < 2; ++h) {
      #pragma unroll
      for (int kk = 0; kk < 2; ++kk) {
        long a[4], b[4];
        const int pg = ((kk << 1) + (qd >> 1)) ^ sfr;
        #pragma unroll
        for (int i = 0; i < 4; ++i)
          a[i] = *(const long*)&lA[h][(wm * 64 + i * 16 + cl) * 64 + pg * 16 + half8];
        #pragma unroll
        for (int j = 0; j < 4; ++j)
          b[j] = *(const long*)&lB[h][(wn * 64 + j * 16 + cl) * 64 + pg * 16 + half8];
        #pragma unroll
        for (int i = 0; i < 4; ++i)
          #pragma unroll
          for (int j = 0; j < 4; ++j)
            acc[i][j] = __builtin_amdgcn_mfma_f32_16x16x32_fp8_fp8(a[i], b[j], acc[i][j], 0, 0, 0);
      }
    }
    __syncthreads();
  }

  // epilogue: exp(acc/32) causal -> bf16 probs + partial row sums
  bf16_t* probs = probs_g + (long)bz * S * S;
  #pragma unroll
  for (int i = 0; i < 4; ++i) {
    const int gm0 = m0 + wm * 64 + i * 16 + qd * 4;
    float ls[4] = {0.f, 0.f, 0.f, 0.f};
    #pragma unroll
    for (int j = 0; j < 4; ++j) {
      const int gn = n0 + wn * 64 + j * 16 + cl;
      #pragma unroll
      for (int r = 0; r < 4; ++r) {
        const int gm = gm0 + r;
        const float e = (gn <= gm) ? __expf(acc[i][j][r] * 0.03125f) : 0.0f;
        probs[(long)gm * S + gn] = (bf16_t)e;
        ls[r] += e;
      }
    }
    #pragma unroll
    for (int r = 0; r < 4; ++r) {
      float v = ls[r];
      v += __shfl_xor(v, 1); v += __shfl_xor(v, 2);
      v += __shfl_xor(v, 4); v += __shfl_xor(v, 8);
      if (cl == 0)
        part[((long)bz * S + (gm0 + r)) * 32 + tn * 2 + wn] = v;
    }
  }
}

// Final PV(+folded Wo): 512 blocks (2/CU, block-count-capped) -> NSUB=2
// (BK=128, 64 KB LDS) doubles MFMA-per-barrier at no occupancy cost.
// Per-CU exact K balance: idx<32 take long-K m's {15,13,11,9}-half, idx>=32
// take {0,2,4,6}+half -> every CU gets exactly 17 k-tiles.
// Computes inv row sums in the prologue (folds reduce_invl kernel).
__global__ __launch_bounds__(256, 2) void gemm_pv_out(
    const bf16_t* __restrict__ probs, const bf16_t* __restrict__ vwT,
    float* out, const float* __restrict__ part, const float* __restrict__ bo)
{
  __shared__ __align__(16) bf16_t lA[2 * 128 * 64], lB[2 * 128 * 64];
  __shared__ float invl_s[128];
  const int l = blockIdx.x, xcd = l & 7, idx = l >> 3;
  const int bz = xcd >> 1, half = xcd & 1;
  const int g = (idx >> 3) & 3, tn = idx & 7;
  const int tm = (idx < 32) ? (15 - half - 2 * g) : (2 * g + half);
  const int kmax = (tm + 1) * 128;

  if (threadIdx.x < 128) {                   // invl for this tile's 128 rows
    const int row = tm * 128 + threadIdx.x;
    const int cnt = (tm + 1) * 2;            // valid partials (stride-32 slab)
    const float* p = part + ((long)bz * S + row) * 32;
    float s = 0.f;
    for (int j = 0; j < cnt; ++j) s += p[j];
    invl_s[threadIdx.x] = 1.0f / s;
  }
  __syncthreads();

  gemm_body<5, 2>(tm, tn, bz, probs + (long)bz * S * S, vwT + (long)bz * D * S,
                  out, (void*)bo, nullptr, invl_s, 2048, kmax, lA, lB);
}

// WvoT[c][i] = sum_n Wv[i][n] * Wo[n][c]  (so vw = x @ (Wv@Wo)).
__global__ __launch_bounds__(256, 4) void gemm_wvo(
    const bf16_t* __restrict__ WoT, const bf16_t* __restrict__ WvN,
    bf16_t* WvoT)
{
  __shared__ __align__(16) bf16_t lA[128 * 64], lB[128 * 64];
  gemm_body<4, 1>(blockIdx.x, blockIdx.y, 0, WoT, WvN, WvoT, nullptr, nullptr,
                  nullptr, 1024, 1024, lA, lB);
}

// fp32 -> bf16 elementwise (x), 4 elems/thread
__global__ __launch_bounds__(256) void cvt_x(
    const float4* __restrict__ in, bf16x4* __restrict__ out, int n4)
{
  const int i = blockIdx.x * 256 + threadIdx.x;
  if (i >= n4) return;
  float4 f = in[i];
  bf16x4 o;
  o.x = (__bf16)f.x; o.y = (__bf16)f.y; o.z = (__bf16)f.z; o.w = (__bf16)f.w;
  out[i] = o;
}

// Weights -> bf16. z=0: Wq^T -> slot0; z=1: Wk^T -> slot1; z=3: Wo^T -> slot4
// (transposed via LDS). z=2: Wv plain cast (natural [i][n]) -> slot3.
// Slot 2 (WvoT) is filled by gemm_wvo.
__global__ __launch_bounds__(256) void cvt_w_t4(
    const float* __restrict__ W0, const float* __restrict__ W1,
    const float* __restrict__ W2, const float* __restrict__ W3,
    bf16_t* __restrict__ dst)
{
  const int zmap[4] = {0, 1, 3, 4};
  const float* W = (blockIdx.z == 0) ? W0 : (blockIdx.z == 1) ? W1
                 : (blockIdx.z == 2) ? W2 : W3;
  bf16_t* WT = dst + (size_t)zmap[blockIdx.z] * D * D;
  const int bx = blockIdx.x, by = blockIdx.y;
  const int tx = threadIdx.x & 31, ty = threadIdx.x >> 5;  // 32 x 8

  if (blockIdx.z == 2) {                      // Wv: plain cast, no transpose
    #pragma unroll
    for (int dy = 0; dy < 32; dy += 8) {
      const long idx = (long)(by * 32 + ty + dy) * 1024 + bx * 32 + tx;
      WT[idx] = (bf16_t)W[idx];
    }
    return;
  }

  __shared__ float t[32][33];
  #pragma unroll
  for (int dy = 0; dy < 32; dy += 8)
    t[ty + dy][tx] = W[(long)(by * 32 + ty + dy) * 1024 + bx * 32 + tx];
  __syncthreads();
  #pragma unroll
  for (int dy = 0; dy < 32; dy += 8)
    WT[(long)(bx * 32 + ty + dy) * 1024 + by * 32 + tx] = (bf16_t)t[tx][ty + dy];
}

// bias build: blocks 0..255 -> bvo[c] = sum_e bv[e]*WoT[c][e], one wave per
// column (coalesced row read + butterfly). Blocks 256..259 copy bq/bk.
__global__ __launch_bounds__(256) void bias_build(
    const float* __restrict__ bq, const float* __restrict__ bk,
    const float* __restrict__ bv, const bf16_t* __restrict__ WoT,
    float* __restrict__ o)
{
  const int b = blockIdx.x;
  if (b >= 256) {
    const int i = (b - 256) * 256 + threadIdx.x;   // 0..1023
    o[i] = bq[i];
    o[1024 + i] = bk[i];
    return;
  }
  const int wave = threadIdx.x >> 6, lane = threadIdx.x & 63;
  const int c = b * 4 + wave;
  const bf16_t* row = WoT + (long)c * 1024 + lane * 16;
  const float*  bvp = bv + lane * 16;
  float s = 0.f;
  #pragma unroll
  for (int j = 0; j < 16; ++j) s += bvp[j] * (float)row[j];
  #pragma unroll
  for (int sh = 32; sh > 0; sh >>= 1) s += __shfl_xor(s, sh, 64);
  if (lane == 0) o[2048 + c] = s;
}

// ---------------------------------------------------------------------------
extern "C" void kernel_launch(void* const* d_in, const int* in_sizes, int n_in,
                              void* d_out, int out_size, void* d_ws, size_t ws_size,
                              hipStream_t stream) {
  const float* x  = (const float*)d_in[0];
  const float* Wq = (const float*)d_in[1];
  const float* bq = (const float*)d_in[2];
  const float* Wk = (const float*)d_in[3];
  const float* bk = (const float*)d_in[4];
  const float* Wv = (const float*)d_in[5];
  const float* bv = (const float*)d_in[6];
  const float* Wo = (const float*)d_in[7];
  const float* bo = (const float*)d_in[8];
  float* out = (float*)d_out;

  size_t off = 0;
  auto alloc = [&](size_t bytes) -> void* {
    void* p = (char*)d_ws + off;
    off += (bytes + 255) & ~(size_t)255;
    return p;
  };
  bf16_t* x_b   = (bf16_t*)alloc((size_t)MF * D * 2);          // 16.8 MB
  bf16_t* Wall  = (bf16_t*)alloc((size_t)5 * D * D * 2);       // [WqT|WkT|WvoT|WvN|WoT]
  float*  bqkv  = (float*) alloc((size_t)3 * D * 4);
  uint8_t* q8   = (uint8_t*)alloc((size_t)MF * D);             // 8.4 MB fp8
  uint8_t* k8   = (uint8_t*)alloc((size_t)MF * D);             // 8.4 MB fp8
  bf16_t* vwT_b = (bf16_t*)alloc((size_t)BATCH * D * S * 2);   // [b][D][S]
  bf16_t* probs = (bf16_t*)alloc((size_t)BATCH * S * S * 2);   // 33.5 MB
  float*  part  = (float*) alloc((size_t)MF * 32 * 4);         // 1 MB
  bf16_t* WqkvT = Wall;                       // stacked B for QKV: [3D][D]
  bf16_t* WvoT  = Wall + (size_t)2 * D * D;
  bf16_t* WvN   = Wall + (size_t)3 * D * D;   // Wv natural layout, bf16
  bf16_t* WoT   = Wall + (size_t)4 * D * D;

  // 1. preamble: x -> bf16; weights -> bf16; bias (bvo via WoT, parallel)
  cvt_x<<<dim3((MF * D / 4 + 255) / 256), 256, 0, stream>>>(
      (const float4*)x, (bf16x4*)x_b, MF * D / 4);
  cvt_w_t4<<<dim3(32, 32, 4), 256, 0, stream>>>(Wq, Wk, Wv, Wo, Wall);
  bias_build<<<dim3(260), 256, 0, stream>>>(bq, bk, bv, WoT, bqkv);

  // 2. WvoT = (Wv@Wo)^T folded weight (so PV emits the final output directly)
  gemm_wvo<<<dim3(8, 8), 256, 0, stream>>>(WoT, WvN, WvoT);

  // 3. fused projection: q/k in fp8 e4m3, vw bf16 transposed
  gemm_qkv<<<dim3(64, 24), 256, 0, stream>>>(x_b, WqkvT, q8, k8, vwT_b, bqkv);

  // 4. scores (fp8 MFMA, 128x128 + BK=128) -> exp(./32) bf16 probs + partials
  gemm_sc8<<<dim3(544), 256, 0, stream>>>(q8, k8, probs, part);

  // 5. out = (P vw) * invl + bo  (final, fp32, BK=128; invl in prologue)
  gemm_pv_out<<<dim3(512), 256, 0, stream>>>(probs, vwT_b, out, part, bo);
}